// Round 13
// baseline (1428.949 us; speedup 1.0000x reference)
//
#include <hip/hip_runtime.h>
#include <cfloat>
#include <cmath>

#define NROWS 32768
#define NTOK  8192
#define DIM   768
#define KSPLIT 384   // OpenBLAS sgemm kc — K=768 -> two sequential fp32 chains (verified R4)

// fallback (R4) tiling
#define BM 64
#define BN 128
#define BK 32
#define NT 512

// float offsets in d_out (concatenated outputs, all read back as f32)
#define Q_OFF   0
#define EI_OFF  (NROWS*DIM)          // 25165824
#define TV_OFF  (EI_OFF + NROWS)     // 25198592
#define TI_OFF  (TV_OFF + NROWS*3)   // 25296896

typedef short short8 __attribute__((ext_vector_type(8)));
typedef float f32x4 __attribute__((ext_vector_type(4)));
typedef float f32x16 __attribute__((ext_vector_type(16)));

// ---------------------------------------------------------------- numpy-exact row sum of squares
// (verified bit-exact in R4 — do not touch)
__global__ __launch_bounds__(256)
void np_norm_kernel(const float* __restrict__ x, float* __restrict__ o) {
#pragma clang fp contract(off)
  const int wid = (blockIdx.x * 256 + threadIdx.x) >> 6;  // one wave per row
  const int lane = threadIdx.x & 63;
  const float* p = x + (size_t)wid * DIM + (lane >> 3) * 96 + (lane & 7);
  float v = p[0];
  float r = v * v;
#pragma unroll
  for (int k = 1; k < 12; k++) {
    float w = p[8 * k];
    float sq = w * w;
    r = r + sq;
  }
#pragma unroll
  for (int m = 1; m < 64; m <<= 1) {
    float other = __shfl_xor(r, m, 64);
    r = r + other;
  }
  if (lane == 0) o[wid] = r;
}

// ---------------------------------------------------------------- helpers
__device__ __forceinline__ bool dless(float a, int ai, float b, int bi_) {
  return (a < b) || (a == b && ai < bi_);
}

__device__ __forceinline__ void ins4(float (&v)[4], int (&x)[4], float c, int ci) {
  if (dless(c, ci, v[3], x[3])) {
    v[3] = c; x[3] = ci;
    if (dless(v[3], x[3], v[2], x[2])) { float tv = v[2]; int ti = x[2]; v[2] = v[3]; x[2] = x[3]; v[3] = tv; x[3] = ti; }
    if (dless(v[2], x[2], v[1], x[1])) { float tv = v[1]; int ti = x[1]; v[1] = v[2]; x[1] = x[2]; v[2] = tv; x[2] = ti; }
    if (dless(v[1], x[1], v[0], x[0])) { float tv = v[0]; int ti = x[0]; v[0] = v[1]; x[0] = x[1]; v[1] = tv; x[1] = ti; }
  }
}

// merge-path insert (with index tie-break)
__device__ __forceinline__ void ins8(float (&v)[8], int (&x)[8], float c, int ci) {
  if (dless(c, ci, v[7], x[7])) {
    v[7] = c; x[7] = ci;
#pragma unroll
    for (int k = 7; k > 0; k--) {
      if (dless(v[k], x[k], v[k - 1], x[k - 1])) {
        float tv = v[k - 1]; int ti = x[k - 1];
        v[k - 1] = v[k]; x[k - 1] = x[k];
        v[k] = tv; x[k] = ti;
      }
    }
  }
}

// hot-path insert: caller guarantees c < v[7]; branchless min/max levels, value-only order
__device__ __forceinline__ void ins8v(float (&v)[8], int (&x)[8], float c, int ci) {
  v[7] = c; x[7] = ci;
#pragma unroll
  for (int k = 7; k > 0; k--) {
    const bool sw = v[k] < v[k - 1];
    const float lo = fminf(v[k], v[k - 1]);
    const float hi = fmaxf(v[k], v[k - 1]);
    const int xlo = sw ? x[k] : x[k - 1];
    const int xhi = sw ? x[k - 1] : x[k];
    v[k - 1] = lo; v[k] = hi;
    x[k - 1] = xlo; x[k] = xhi;
  }
}

__device__ __forceinline__ unsigned short f2bf(float f) {  // RNE fp32 -> bf16
  unsigned int u = __float_as_uint(f);
  u += 0x7FFFu + ((u >> 16) & 1u);
  return (unsigned short)(u >> 16);
}

typedef const __attribute__((address_space(1))) void* gas1_t;
typedef __attribute__((address_space(3))) void* las3_t;
__device__ __forceinline__ void gl16(const void* g, void* s) {
  // async global->LDS, 16B per lane; LDS dest = wave-uniform base + lane*16
  __builtin_amdgcn_global_load_lds((gas1_t)g, (las3_t)s, 16, 0, 0);
}

// ---------------------------------------------------------------- bf16 transposed pre-convert
// out layout: 16B chunk (Q, row) at out + (Q*nrows + row)*8 ushorts, Q = k-octet (0..95)
__global__ __launch_bounds__(256)
void cvtT_kernel(const float* __restrict__ in, unsigned short* __restrict__ out, int nrows) {
  __shared__ int4 tile[32][33];
  const int r0 = blockIdx.x * 32;
  const int Q0 = blockIdx.y * 32;
  const int t = threadIdx.x;
#pragma unroll
  for (int i = 0; i < 4; ++i) {
    const int f = t + i * 256;
    const int qi = f & 31, ri = f >> 5;
    const float4* p = (const float4*)(in + (size_t)(r0 + ri) * DIM + (Q0 + qi) * 8);
    const float4 a = p[0], b = p[1];
    union { unsigned short u[8]; int4 v; } pk;
    pk.u[0] = f2bf(a.x); pk.u[1] = f2bf(a.y); pk.u[2] = f2bf(a.z); pk.u[3] = f2bf(a.w);
    pk.u[4] = f2bf(b.x); pk.u[5] = f2bf(b.y); pk.u[6] = f2bf(b.z); pk.u[7] = f2bf(b.w);
    tile[qi][ri] = pk.v;
  }
  __syncthreads();
#pragma unroll
  for (int i = 0; i < 4; ++i) {
    const int f = t + i * 256;
    const int ri = f & 31, qi = f >> 5;
    *(int4*)(out + ((size_t)(Q0 + qi) * nrows + r0 + ri) * 8) = tile[qi][ri];
  }
}

// ---------------------------------------------------------------- stage 1: swapped-operand MFMA rank
// 256-thread blocks (4 waves). Wave w owns rows row0+w*32..+31 x its col-HALF (4096 cols);
// capture = per-row TOP-8 per half (R5-R11's proven criterion) -> topp 16/row unchanged.
// e-LDS super-tile 128 cols x 64 k = 16KB, ring-2 = 32KB -> with acc halved (64 VGPR)
// and __launch_bounds__(256,3): 3 blocks/CU (12 waves/CU). Direct per-wave topp write,
// counted vmcnt(8), x direct-from-global 2-bank ping-pong, setprio on MFMA.
__global__ __launch_bounds__(256, 3)
void vq_rank(const unsigned short* __restrict__ xbT, const unsigned short* __restrict__ ebT,
             const float* __restrict__ e2g, unsigned short* __restrict__ topp) {
  __shared__ __align__(16) unsigned char esm[2][16384];  // [buf][k-octet 0..7][col 0..127] 16B chunks

  const int tid = threadIdx.x;
  const int l = tid & 63;
  const int w = tid >> 6;          // 0..3 (row-group: 32 rows each)
  const int l31 = l & 31, h = l >> 5;

  // bijective XCD swizzle (512 % 8 == 0); same-XCD blocks share the e col-half
  const int bid = (int)blockIdx.x;
  const int sbid = (bid & 7) * 64 + (bid >> 3);
  const int chalf = sbid >> 8;          // 0..1
  const int rowblk = sbid & 255;        // 0..255
  const int row0 = rowblk * 128;
  const int cg0 = chalf * 4096;

  // per-lane x base (ushort units): Q = 4*kt + 2*s + h, row = row0 + w*32 + l31
  const size_t xinv = ((size_t)h * NROWS + row0 + w * 32 + l31) * 8;

  float bv[8]; int bi[8];
#pragma unroll
  for (int c = 0; c < 8; ++c) { bv[c] = FLT_MAX; bi[c] = 0x7FFFFFFF; }

  f32x16 acc[4];
#pragma unroll
  for (int ei = 0; ei < 4; ++ei) acc[ei] = (f32x16)0.f;

  short8 xb0[2], xb1[2];   // ping-pong x-fragment banks [s]

  // stage super-tile (64 k = 8 octets x 128 cols = 16KB): 4 gl16 per thread
#define STAGE(BN_, KS, STRIP)                                                   \
  {                                                                             \
    const int Qb = (KS) * 8 + (tid >> 7);                                       \
    const int colg = cg0 + (STRIP) * 128 + (tid & 127);                         \
    _Pragma("unroll")                                                           \
    for (int c = 0; c < 4; ++c) {                                               \
      gl16(ebT + ((size_t)(Qb + 2 * c) * NTOK + colg) * 8,                      \
           &esm[BN_][c * 4096 + tid * 16]);                                     \
    }                                                                           \
  }

#define XLOAD(XB, KT)                                                           \
  {                                                                             \
    const unsigned short* xp = xbT + (size_t)(4 * (KT)) * (NROWS * 8);          \
    XB[0] = *(const short8*)(xp + xinv);                                        \
    XB[1] = *(const short8*)(xp + 2 * NROWS * 8 + xinv);                        \
  }

  // one K-step (32 k) from buffer P, sub-step J (0,1); computes XBC, prefetches XBN
#define ITER(P, J, XBC, XBN)                                                    \
  {                                                                             \
    XLOAD(XBN, xkt) if (++xkt == 24) xkt = 0;                                   \
    const unsigned char* ebp = &esm[P][0];                                      \
    short8 af[4];                                                               \
    _Pragma("unroll")                                                           \
    for (int ei = 0; ei < 4; ++ei)                                              \
      af[ei] = *(const short8*)(ebp + (J) * 8192 + h * 2048 + (ei * 32 + l31) * 16); \
    __builtin_amdgcn_s_setprio(1);                                              \
    _Pragma("unroll")                                                           \
    for (int ei = 0; ei < 4; ++ei)                                              \
      acc[ei] = __builtin_amdgcn_mfma_f32_32x32x16_bf16(af[ei], XBC[0], acc[ei], 0, 0, 0); \
    __builtin_amdgcn_s_setprio(0);                                              \
    _Pragma("unroll")                                                           \
    for (int ei = 0; ei < 4; ++ei)                                              \
      af[ei] = *(const short8*)(ebp + (J) * 8192 + 4096 + h * 2048 + (ei * 32 + l31) * 16); \
    __builtin_amdgcn_s_setprio(1);                                              \
    _Pragma("unroll")                                                           \
    for (int ei = 0; ei < 4; ++ei)                                              \
      acc[ei] = __builtin_amdgcn_mfma_f32_32x32x16_bf16(af[ei], XBC[1], acc[ei], 0, 0, 0); \
    __builtin_amdgcn_s_setprio(0);                                              \
  }

  // SELECT over finished 128-col strip: s = e2[col] - 2*dot (x2 row-constant: rank-invariant)
#define SELECT(SC0)                                                             \
  {                                                                             \
    _Pragma("unroll")                                                           \
    for (int ei = 0; ei < 4; ++ei) {                                            \
      const int cb = (SC0) + ei * 32 + 4 * h;                                   \
      float4 e2q[4];                                                            \
      _Pragma("unroll")                                                         \
      for (int q = 0; q < 4; ++q)                                               \
        e2q[q] = *(const float4*)(e2g + cb + q * 8);                            \
      _Pragma("unroll")                                                         \
      for (int q = 0; q < 4; ++q) {                                             \
        const float c0 = fmaf(-2.f, acc[ei][q * 4 + 0], e2q[q].x);              \
        const float c1 = fmaf(-2.f, acc[ei][q * 4 + 1], e2q[q].y);              \
        const float c2 = fmaf(-2.f, acc[ei][q * 4 + 2], e2q[q].z);              \
        const float c3 = fmaf(-2.f, acc[ei][q * 4 + 3], e2q[q].w);              \
        if (c0 < bv[7]) ins8v(bv, bi, c0, cb + q * 8 + 0);                      \
        if (c1 < bv[7]) ins8v(bv, bi, c1, cb + q * 8 + 1);                      \
        if (c2 < bv[7]) ins8v(bv, bi, c2, cb + q * 8 + 2);                      \
        if (c3 < bv[7]) ins8v(bv, bi, c3, cb + q * 8 + 3);                      \
      }                                                                         \
    }                                                                           \
    _Pragma("unroll")                                                           \
    for (int ei = 0; ei < 4; ++ei) acc[ei] = (f32x16)0.f;                       \
  }

  // super-stage body: stage tile g+1, counted wait for tile g, 2 K-steps, barrier.
#define BODY(P, DO_S, WAITS)                                                    \
  {                                                                             \
    if (DO_S) {                                                                 \
      STAGE(P ^ 1, nks, nstrip)                                                 \
      if (++nks == 12) { nks = 0; ++nstrip; }                                   \
    }                                                                           \
    asm volatile(WAITS ::: "memory");                                           \
    __builtin_amdgcn_s_barrier();                                               \
    asm volatile("" ::: "memory");                                              \
    ITER(P, 0, xb0, xb1)                                                        \
    ITER(P, 1, xb1, xb0)                                                        \
    if (++kc == 12) { SELECT(scol0) kc = 0; scol0 += 128; }                     \
    __builtin_amdgcn_s_barrier();                                               \
  }

  // prologue: super-tile 0 + x bank for K-step 0
  STAGE(0, 0, 0)
  XLOAD(xb0, 0)
  asm volatile("s_waitcnt vmcnt(0)" ::: "memory");
  __builtin_amdgcn_s_barrier();

  int nks = 1, nstrip = 0;     // coords of next super-tile (body g stages tile g+1)
  int xkt = 1;                 // K-step of next XLOAD
  int kc = 0, scol0 = cg0;     // strip progress / SELECT strip base

  // 384 bodies: 191 pairs + 2 tail (32 strips x 12 bodies)
#pragma unroll 1
  for (int gp = 0; gp < 191; ++gp) {
    BODY(0, 1, "s_waitcnt vmcnt(8)")
    BODY(1, 1, "s_waitcnt vmcnt(8)")
  }
  BODY(0, 1, "s_waitcnt vmcnt(8)")
  BODY(1, 0, "s_waitcnt vmcnt(4)")
#undef BODY
#undef SELECT
#undef ITER
#undef XLOAD
#undef STAGE

  // h-merge (lanes l and l+32 hold the same x-row, disjoint col subsets)
  {
    float ov[8]; int oi[8];
#pragma unroll
    for (int c = 0; c < 8; ++c) {
      ov[c] = __shfl_xor(bv[c], 32, 64);
      oi[c] = __shfl_xor(bi[c], 32, 64);
    }
#pragma unroll
    for (int c = 0; c < 8; ++c) ins8(bv, bi, ov[c], oi[c]);
  }

  // write this half's top-8 per row (no cross-wave merge needed)
  if (l < 32) {
    const int row = row0 + w * 32 + l31;
    unsigned short* dst = topp + (size_t)row * 16 + chalf * 8;
#pragma unroll
    for (int c = 0; c < 8; ++c) dst[c] = (unsigned short)bi[c];
  }
}

// ---------------------------------------------------------------- stage 2: exact fp32 refine of 16 candidates
__global__ __launch_bounds__(256)
void vq_refine16(const float* __restrict__ x, const float* __restrict__ E,
                 const float* __restrict__ x2, const float* __restrict__ e2,
                 const unsigned short* __restrict__ topp, float* __restrict__ out) {
  const int gid = blockIdx.x * 256 + threadIdx.x;
  const int row = gid >> 4;
  const int s = gid & 15;
  const int myc = topp[(size_t)row * 16 + s];

  const float4* xr = (const float4*)(x + (size_t)row * DIM);
  const float4* er = (const float4*)(E + (size_t)myc * DIM);
  // two sequential fp32 fma chains split at KSPLIT (identical to R4's verified arithmetic)
  float accA = 0.f, accB = 0.f;
#pragma unroll 8
  for (int q = 0; q < KSPLIT / 4; ++q) {
    const float4 a = xr[q], b = er[q];
    accA = fmaf(a.x, b.x, accA); accA = fmaf(a.y, b.y, accA);
    accA = fmaf(a.z, b.z, accA); accA = fmaf(a.w, b.w, accA);
  }
#pragma unroll 8
  for (int q = KSPLIT / 4; q < DIM / 4; ++q) {
    const float4 a = xr[q], b = er[q];
    accB = fmaf(a.x, b.x, accB); accB = fmaf(a.y, b.y, accB);
    accB = fmaf(a.z, b.z, accB); accB = fmaf(a.w, b.w, accB);
  }
  const float d = fmaf(-2.0f, accA + accB, x2[row] + e2[myc]);

  // gather all 16 candidates of this row within the 16-lane group
  const int base = (threadIdx.x & 63) & ~15;
  float dv[16]; int cv[16];
#pragma unroll
  for (int t = 0; t < 16; ++t) {
    dv[t] = __shfl(d, base + t, 64);
    cv[t] = __shfl(myc, base + t, 64);
  }
  // 4 bubble passes -> slots 0..3 are the exact ascending top-4
#pragma unroll
  for (int a = 0; a < 4; ++a)
#pragma unroll
    for (int b = 15; b > a; --b) {
      const bool sw = (dv[b] < dv[b - 1]) || (dv[b] == dv[b - 1] && cv[b] < cv[b - 1]);
      if (sw) {
        float td = dv[b]; dv[b] = dv[b - 1]; dv[b - 1] = td;
        int ti = cv[b]; cv[b] = cv[b - 1]; cv[b - 1] = ti;
      }
    }

  if (s == 0) {
    out[EI_OFF + row] = (float)cv[0];
    const double d1 = (double)dv[1], d2 = (double)dv[2], d3 = (double)dv[3];
    double nrm = sqrt(d1 * d1 + d2 * d2 + d3 * d3);
    nrm = fmax(nrm, 1e-12);
    const double t1 = 1.0 / (d1 / nrm + 1e-4);
    const double t2 = 1.0 / (d2 / nrm + 1e-4);
    const double t3 = 1.0 / (d3 / nrm + 1e-4);
    const double mx = fmax(t1, fmax(t2, t3));
    const double e1 = exp(t1 - mx), e2x = exp(t2 - mx), e3 = exp(t3 - mx);
    const double sm = e1 + e2x + e3;
    out[TV_OFF + row * 3 + 0] = (float)(e1 / sm);
    out[TV_OFF + row * 3 + 1] = (float)(e2x / sm);
    out[TV_OFF + row * 3 + 2] = (float)(e3 / sm);
    out[TI_OFF + row * 3 + 0] = (float)cv[1];
    out[TI_OFF + row * 3 + 1] = (float)cv[2];
    out[TI_OFF + row * 3 + 2] = (float)cv[3];
  }

  // quantize = embed[argmin]: 16-lane cooperative float4 copy
  const float4* src = (const float4*)(E + (size_t)cv[0] * DIM);
  float4* dst = (float4*)(out + Q_OFF + (size_t)row * DIM);
#pragma unroll
  for (int k = 0; k < 12; ++k) dst[s + k * 16] = src[s + k * 16];
}

// ---------------------------------------------------------------- fallback: R4's passing fused fp32 kernel
__global__ __launch_bounds__(NT, 4)
void vq_main(const float* __restrict__ A, const float* __restrict__ E,
             const float* __restrict__ x2, const float* __restrict__ e2,
             float* __restrict__ out) {
  __shared__ float a_s[BK][BM + 4];
  __shared__ float b_s[BK][BN + 4];

  const int tid = threadIdx.x;
  const int tx = tid & 15;
  const int ty = tid >> 4;
  const int row0 = blockIdx.x * BM;

  const float x2r[2] = { x2[row0 + ty * 2 + 0], x2[row0 + ty * 2 + 1] };

  float bv[2][4];
  int   bi[2][4];
#pragma unroll
  for (int i = 0; i < 2; i++)
#pragma unroll
    for (int c = 0; c < 4; c++) { bv[i][c] = FLT_MAX; bi[i][c] = 0x7FFFFFFF; }

#define GEMM_STEP(k0, ACC)                                                       \
    {                                                                            \
      __syncthreads();                                                           \
      {                                                                          \
        const int r = tid >> 3, kq = tid & 7;                                    \
        const float4 v = *(const float4*)(A + (size_t)(row0 + r) * DIM + (k0 + kq * 4)); \
        a_s[kq * 4 + 0][r] = v.x; a_s[kq * 4 + 1][r] = v.y;                      \
        a_s[kq * 4 + 2][r] = v.z; a_s[kq * 4 + 3][r] = v.w;                      \
        _Pragma("unroll")                                                        \
        for (int s = 0; s < 2; s++) {                                            \
          const int fi = tid + s * NT;                                           \
          const int rb = fi >> 3, kb = fi & 7;                                   \
          const float4 w = *(const float4*)(E + (size_t)(col0 + rb) * DIM + (k0 + kb * 4)); \
          b_s[kb * 4 + 0][rb] = w.x; b_s[kb * 4 + 1][rb] = w.y;                  \
          b_s[kb * 4 + 2][rb] = w.z; b_s[kb * 4 + 3][rb] = w.w;                  \
        }                                                                        \
      }                                                                          \
      __syncthreads();                                                           \
      _Pragma("unroll")                                                          \
      for (int k = 0; k < BK; k++) {                                             \
        const float2 a2 = *(const float2*)&a_s[k][ty * 2];                       \
        float br[8];                                                             \
        *(float4*)(br)     = *(const float4*)&b_s[k][tx * 8];                    \
        *(float4*)(br + 4) = *(const float4*)&b_s[k][tx * 8 + 4];                \
        _Pragma("unroll")                                                        \
        for (int j = 0; j < 8; j++) {                                            \
          ACC[0][j] = fmaf(a2.x, br[j], ACC[0][j]);                              \
          ACC[1][j] = fmaf(a2.y, br[j], ACC[1][j]);                              \
        }                                                                        \
      }                                                                          \
    }

  for (int ct = 0; ct < NTOK / BN; ++ct) {
    const int col0 = ct * BN;

    float accA[2][8], accB[2][8];
#pragma unroll
    for (int i = 0; i < 2; i++)
#pragma unroll
      for (int j = 0; j < 8; j++) { accA[i][j] = 0.f; accB[i][j] = 0.f; }

    for (int k0 = 0; k0 < KSPLIT; k0 += BK) GEMM_STEP(k0, accA)
    for (int k0 = KSPLIT; k0 < DIM; k0 += BK) GEMM_STEP(k0, accB)

    float e2v[8];
    *(float4*)(e2v)     = *(const float4*)(e2 + col0 + tx * 8);
    *(float4*)(e2v + 4) = *(const float4*)(e2 + col0 + tx * 8 + 4);
#pragma unroll
    for (int i = 0; i < 2; i++) {
#pragma unroll
      for (int j = 0; j < 8; j++) {
        const float dot = accA[i][j] + accB[i][j];
        const float se = x2r[i] + e2v[j];
        const float d = fmaf(-2.0f, dot, se);
        const int ci = col0 + tx * 8 + j;
        ins4(bv[i], bi[i], d, ci);
      }
    }
  }
#undef GEMM_STEP

#pragma unroll
  for (int m = 1; m < 16; m <<= 1) {
#pragma unroll
    for (int i = 0; i < 2; i++) {
      float ov[4]; int oi[4];
#pragma unroll
      for (int c = 0; c < 4; c++) {
        ov[c] = __shfl_xor(bv[i][c], m, 64);
        oi[c] = __shfl_xor(bi[i][c], m, 64);
      }
#pragma unroll
      for (int c = 0; c < 4; c++) ins4(bv[i], bi[i], ov[c], oi[c]);
    }
  }

#pragma unroll
  for (int i = 0; i < 2; i++) {
    if (tx == i) {
      const int gr = row0 + ty * 2 + i;
      out[EI_OFF + gr] = (float)bi[i][0];
      const double d1 = (double)bv[i][1], d2 = (double)bv[i][2], d3 = (double)bv[i][3];
      double nrm = sqrt(d1 * d1 + d2 * d2 + d3 * d3);
      nrm = fmax(nrm, 1e-12);
      const double t1 = 1.0 / (d1 / nrm + 1e-4);
      const double t2 = 1.0 / (d2 / nrm + 1e-4);
      const double t3 = 1.0 / (d3 / nrm + 1e-4);
      const double mx = fmax(t1, fmax(t2, t3));
      const double e1 = exp(t1 - mx), e2x = exp(t2 - mx), e3 = exp(t3 - mx);
      const double s = e1 + e2x + e3;
      out[TV_OFF + gr * 3 + 0] = (float)(e1 / s);
      out[TV_OFF + gr * 3 + 1] = (float)(e2x / s);
      out[TV_OFF + gr * 3 + 2] = (float)(e3 / s);
      out[TI_OFF + gr * 3 + 0] = (float)bi[i][1];
      out[TI_OFF + gr * 3 + 1] = (float)bi[i][2];
      out[TI_OFF + gr * 3 + 2] = (float)bi[i][3];
    }
  }

  __syncthreads();
  int* idx_sh = (int*)&a_s[0][0];
  if (tx == 0) idx_sh[ty * 2 + 0] = bi[0][0];
  if (tx == 1) idx_sh[ty * 2 + 1] = bi[1][0];
  __syncthreads();

  for (int f = tid; f < BM * (DIM / 4); f += NT) {
    const int r = f / (DIM / 4);
    const int c = f % (DIM / 4);
    const int e = idx_sh[r];
    const float4 v = *(const float4*)(E + (size_t)e * DIM + c * 4);
    *(float4*)(out + Q_OFF + (size_t)(row0 + r) * DIM + c * 4) = v;
  }
}

// ---------------------------------------------------------------- launch
extern "C" void kernel_launch(void* const* d_in, const int* in_sizes, int n_in,
                              void* d_out, int out_size, void* d_ws, size_t ws_size,
                              hipStream_t stream) {
  const float* x = (const float*)d_in[0];  // inputs_flatten [32768,768]
  const float* E = (const float*)d_in[1];  // embed          [8192,768]
  float* out = (float*)d_out;

  // ws layout (bytes) — identical footprint to R5-R12 (proven to fit)
  unsigned char* ws = (unsigned char*)d_ws;
  float* e2 = (float*)ws;                                   // 8192 f32
  float* x2 = (float*)(ws + 32768);                         // 32768 f32
  unsigned short* topp = (unsigned short*)(ws + 32768 + 131072);  // 32768*16 u16 = 1MB
  unsigned short* xbT = (unsigned short*)(ws + 32768 + 131072 + 1048576);
  unsigned short* ebT = xbT + (size_t)NROWS * DIM;
  const size_t need = 32768 + 131072 + 1048576 +
                      (size_t)NROWS * DIM * 2 + (size_t)NTOK * DIM * 2;

  np_norm_kernel<<<NTOK / 4, 256, 0, stream>>>(E, e2);
  np_norm_kernel<<<NROWS / 4, 256, 0, stream>>>(x, x2);

  if (ws_size >= need) {
    cvtT_kernel<<<dim3(NROWS / 32, 3), 256, 0, stream>>>(x, xbT, NROWS);
    cvtT_kernel<<<dim3(NTOK / 32, 3), 256, 0, stream>>>(E, ebT, NTOK);
    vq_rank<<<512, 256, 0, stream>>>(xbT, ebT, e2, topp);
    vq_refine16<<<NROWS * 16 / 256, 256, 0, stream>>>(x, E, x2, e2, topp, out);
  } else {
    vq_main<<<NROWS / BM, NT, 0, stream>>>(x, E, x2, e2, out);
  }
}

// Round 14
// 925.659 us; speedup vs baseline: 1.5437x; 1.5437x over previous
//
#include <hip/hip_runtime.h>
#include <cfloat>
#include <cmath>

#define NROWS 32768
#define NTOK  8192
#define DIM   768
#define KSPLIT 384   // OpenBLAS sgemm kc — K=768 -> two sequential fp32 chains (verified R4)

// fallback (R4) tiling
#define BM 64
#define BN 128
#define BK 32
#define NT 512

// float offsets in d_out (concatenated outputs, all read back as f32)
#define Q_OFF   0
#define EI_OFF  (NROWS*DIM)          // 25165824
#define TV_OFF  (EI_OFF + NROWS)     // 25198592
#define TI_OFF  (TV_OFF + NROWS*3)   // 25296896

typedef short short8 __attribute__((ext_vector_type(8)));
typedef float f32x4 __attribute__((ext_vector_type(4)));
typedef float f32x16 __attribute__((ext_vector_type(16)));

// ---------------------------------------------------------------- numpy-exact row sum of squares
// (verified bit-exact in R4 — do not touch)
__global__ __launch_bounds__(256)
void np_norm_kernel(const float* __restrict__ x, float* __restrict__ o) {
#pragma clang fp contract(off)
  const int wid = (blockIdx.x * 256 + threadIdx.x) >> 6;  // one wave per row
  const int lane = threadIdx.x & 63;
  const float* p = x + (size_t)wid * DIM + (lane >> 3) * 96 + (lane & 7);
  float v = p[0];
  float r = v * v;
#pragma unroll
  for (int k = 1; k < 12; k++) {
    float w = p[8 * k];
    float sq = w * w;
    r = r + sq;
  }
#pragma unroll
  for (int m = 1; m < 64; m <<= 1) {
    float other = __shfl_xor(r, m, 64);
    r = r + other;
  }
  if (lane == 0) o[wid] = r;
}

// ---------------------------------------------------------------- helpers
__device__ __forceinline__ bool dless(float a, int ai, float b, int bi_) {
  return (a < b) || (a == b && ai < bi_);
}

__device__ __forceinline__ void ins4(float (&v)[4], int (&x)[4], float c, int ci) {
  if (dless(c, ci, v[3], x[3])) {
    v[3] = c; x[3] = ci;
    if (dless(v[3], x[3], v[2], x[2])) { float tv = v[2]; int ti = x[2]; v[2] = v[3]; x[2] = x[3]; v[3] = tv; x[3] = ti; }
    if (dless(v[2], x[2], v[1], x[1])) { float tv = v[1]; int ti = x[1]; v[1] = v[2]; x[1] = x[2]; v[2] = tv; x[2] = ti; }
    if (dless(v[1], x[1], v[0], x[0])) { float tv = v[0]; int ti = x[0]; v[0] = v[1]; x[0] = x[1]; v[1] = tv; x[1] = ti; }
  }
}

// merge-path insert (with index tie-break, identical semantics to R9 merges)
__device__ __forceinline__ void ins8(float (&v)[8], int (&x)[8], float c, int ci) {
  if (dless(c, ci, v[7], x[7])) {
    v[7] = c; x[7] = ci;
#pragma unroll
    for (int k = 7; k > 0; k--) {
      if (dless(v[k], x[k], v[k - 1], x[k - 1])) {
        float tv = v[k - 1]; int ti = x[k - 1];
        v[k - 1] = v[k]; x[k - 1] = x[k];
        v[k] = tv; x[k] = ti;
      }
    }
  }
}

// hot-path insert: caller guarantees c < v[7]; branchless min/max levels, value-only order
__device__ __forceinline__ void ins8v(float (&v)[8], int (&x)[8], float c, int ci) {
  v[7] = c; x[7] = ci;
#pragma unroll
  for (int k = 7; k > 0; k--) {
    const bool sw = v[k] < v[k - 1];
    const float vmin = fminf(v[k], v[k - 1]);
    const float vmax = fmaxf(v[k], v[k - 1]);
    const int xk1 = sw ? x[k] : x[k - 1];
    const int xk  = sw ? x[k - 1] : x[k];
    v[k - 1] = vmin; v[k] = vmax;
    x[k - 1] = xk1;  x[k] = xk;
  }
}

__device__ __forceinline__ unsigned short f2bf(float f) {  // RNE fp32 -> bf16
  unsigned int u = __float_as_uint(f);
  u += 0x7FFFu + ((u >> 16) & 1u);
  return (unsigned short)(u >> 16);
}

typedef const __attribute__((address_space(1))) void* gas1_t;
typedef __attribute__((address_space(3))) void* las3_t;
__device__ __forceinline__ void gl16(const void* g, void* s) {
  // async global->LDS, 16B per lane; LDS dest = wave-uniform base + lane*16
  __builtin_amdgcn_global_load_lds((gas1_t)g, (las3_t)s, 16, 0, 0);
}

// ---------------------------------------------------------------- bf16 transposed pre-convert
// out layout: 16B chunk (Q, row) at out + (Q*nrows + row)*8 ushorts, Q = k-octet (0..95)
__global__ __launch_bounds__(256)
void cvtT_kernel(const float* __restrict__ in, unsigned short* __restrict__ out, int nrows) {
  const int row = blockIdx.x * 256 + threadIdx.x;
  const int Q = blockIdx.y;
  const float4* p = (const float4*)(in + (size_t)row * DIM + Q * 8);
  const float4 a = p[0], b = p[1];
  union { unsigned short u[8]; int4 v; } pk;
  pk.u[0] = f2bf(a.x); pk.u[1] = f2bf(a.y); pk.u[2] = f2bf(a.z); pk.u[3] = f2bf(a.w);
  pk.u[4] = f2bf(b.x); pk.u[5] = f2bf(b.y); pk.u[6] = f2bf(b.z); pk.u[7] = f2bf(b.w);
  *(int4*)(out + ((size_t)Q * nrows + row) * 8) = pk.v;
}

// ---------------------------------------------------------------- stage 1: swapped-operand MFMA rank
// 256-thread blocks (4 waves, 2wr x 2wc), tile 128 rows x 4096 cols, 2 blocks/CU.
// e-only LDS ring-4 (64KB) + counted vmcnt(12); x direct from global (L3-resident)
// with 2-deep register ping-pong prefetch. Per-candidate screened branchless ins8v.
#define STRIPS 16
#define KSTEPS 24
#define NITER (STRIPS * KSTEPS)

__global__ __launch_bounds__(256, 2)
void vq_rank(const unsigned short* __restrict__ xbT, const unsigned short* __restrict__ ebT,
             const float* __restrict__ e2g, unsigned short* __restrict__ topp) {
  __shared__ __align__(16) unsigned char esm[4][16384];  // [buf][kq 0..3][col 0..255] 16B chunks

  const int tid = threadIdx.x;
  const int l = tid & 63;
  const int w = tid >> 6;          // 0..3
  const int wr = w >> 1, wc = w & 1;
  const int l31 = l & 31, h = l >> 5;

  // bijective XCD swizzle (512 blocks % 8 == 0); same-XCD blocks share the e col-half
  const int bid = (int)blockIdx.x;
  const int sbid = (bid & 7) * 64 + (bid >> 3);
  const int chalf = sbid >> 8;
  const int row0 = (sbid & 255) * 128;
  const int cg0 = chalf * 4096;

  // per-lane x bases (ushort units): Q = 4*kt + 2*s + h, row = row0 + wr*64 + xj*32 + l31
  const size_t xinv0 = ((size_t)h * NROWS + row0 + wr * 64 + l31) * 8;
  const size_t xinv1 = xinv0 + 32 * 8;

  float bv[2][8]; int bi[2][8];
#pragma unroll
  for (int xj = 0; xj < 2; ++xj)
#pragma unroll
    for (int c = 0; c < 8; ++c) { bv[xj][c] = FLT_MAX; bi[xj][c] = 0x7FFFFFFF; }

  f32x16 acc[4][2];
#pragma unroll
  for (int ei = 0; ei < 4; ++ei)
#pragma unroll
    for (int xj = 0; xj < 2; ++xj) acc[ei][xj] = (f32x16)0.f;

  short8 xb0[4], xb1[4];   // ping-pong x-fragment banks [s*2+xj]

#define STAGE_E(BN_, KT, COL0)                                                  \
  {                                                                             \
    const unsigned short* eg = ebT + ((size_t)(4 * (KT)) * NTOK + (COL0) + tid) * 8; \
    gl16(eg,                &esm[BN_][(0 * 256 + w * 64) * 16]);                \
    gl16(eg + NTOK * 8,     &esm[BN_][(1 * 256 + w * 64) * 16]);                \
    gl16(eg + 2 * NTOK * 8, &esm[BN_][(2 * 256 + w * 64) * 16]);                \
    gl16(eg + 3 * NTOK * 8, &esm[BN_][(3 * 256 + w * 64) * 16]);                \
  }

#define XLOAD(XB, KT)                                                           \
  {                                                                             \
    const unsigned short* xp = xbT + (size_t)(4 * (KT)) * (NROWS * 8);          \
    XB[0] = *(const short8*)(xp + xinv0);                                       \
    XB[1] = *(const short8*)(xp + xinv1);                                       \
    XB[2] = *(const short8*)(xp + 2 * NROWS * 8 + xinv0);                       \
    XB[3] = *(const short8*)(xp + 2 * NROWS * 8 + xinv1);                       \
  }

#define COMPUTE(B_, XB)                                                         \
  {                                                                             \
    const unsigned char* ebp = &esm[B_][0];                                     \
    __builtin_amdgcn_s_setprio(1);                                              \
    _Pragma("unroll")                                                           \
    for (int s = 0; s < 2; ++s) {                                               \
      const int kq = s * 2 + h;                                                 \
      short8 af[4];                                                             \
      _Pragma("unroll")                                                         \
      for (int ei = 0; ei < 4; ++ei)                                            \
        af[ei] = *(const short8*)(ebp + (size_t)(kq * 256 + wc * 128 + ei * 32 + l31) * 16); \
      _Pragma("unroll")                                                         \
      for (int ei = 0; ei < 4; ++ei)                                            \
        _Pragma("unroll")                                                       \
        for (int xj = 0; xj < 2; ++xj)                                          \
          acc[ei][xj] = __builtin_amdgcn_mfma_f32_32x32x16_bf16(af[ei], XB[s * 2 + xj], acc[ei][xj], 0, 0, 0); \
    }                                                                           \
    __builtin_amdgcn_s_setprio(0);                                              \
  }

  // SELECT: s = e2[col] - 2*dot (x2 row-constant: rank-invariant); per-candidate screen
#define SELECT(SC0)                                                             \
  {                                                                             \
    _Pragma("unroll")                                                           \
    for (int ei = 0; ei < 4; ++ei) {                                            \
      const int cb = (SC0) + wc * 128 + ei * 32 + 4 * h;                        \
      float4 e2q[4];                                                            \
      _Pragma("unroll")                                                         \
      for (int q = 0; q < 4; ++q)                                               \
        e2q[q] = *(const float4*)(e2g + cb + q * 8);                            \
      _Pragma("unroll")                                                         \
      for (int xj = 0; xj < 2; ++xj) {                                          \
        _Pragma("unroll")                                                       \
        for (int q = 0; q < 4; ++q) {                                           \
          const float c0 = fmaf(-2.f, acc[ei][xj][q * 4 + 0], e2q[q].x);        \
          const float c1 = fmaf(-2.f, acc[ei][xj][q * 4 + 1], e2q[q].y);        \
          const float c2 = fmaf(-2.f, acc[ei][xj][q * 4 + 2], e2q[q].z);        \
          const float c3 = fmaf(-2.f, acc[ei][xj][q * 4 + 3], e2q[q].w);        \
          if (c0 < bv[xj][7]) ins8v(bv[xj], bi[xj], c0, cb + q * 8 + 0);        \
          if (c1 < bv[xj][7]) ins8v(bv[xj], bi[xj], c1, cb + q * 8 + 1);        \
          if (c2 < bv[xj][7]) ins8v(bv[xj], bi[xj], c2, cb + q * 8 + 2);        \
          if (c3 < bv[xj][7]) ins8v(bv[xj], bi[xj], c3, cb + q * 8 + 3);        \
        }                                                                       \
      }                                                                         \
    }                                                                           \
    _Pragma("unroll")                                                           \
    for (int ei = 0; ei < 4; ++ei)                                              \
      _Pragma("unroll")                                                         \
      for (int xj = 0; xj < 2; ++xj) acc[ei][xj] = (f32x16)0.f;                 \
  }

#define BODY(B_, XB, DO_X, DO_S, WAITS)                                         \
  {                                                                             \
    asm volatile(WAITS ::: "memory");                                           \
    __builtin_amdgcn_s_barrier();                                               \
    asm volatile("" ::: "memory");                                              \
    COMPUTE(B_, XB)                                                             \
    if (DO_X) { XLOAD(XB, xkt) if (++xkt == KSTEPS) xkt = 0; }                  \
    if (DO_S) {                                                                 \
      STAGE_E((B_ + 3) & 3, nkt, ncol0)                                         \
      if (++nkt == KSTEPS) { nkt = 0; ncol0 += 256; }                           \
    }                                                                           \
    if (++kc == KSTEPS) { SELECT(scol0) kc = 0; scol0 += 256; }                 \
  }

  // prologue: e tiles 0..2 interleaved with x banks for t=0,1 (FIFO: S0,X0,S1,X1,S2)
  STAGE_E(0, 0, cg0)
  XLOAD(xb0, 0)
  STAGE_E(1, 1, cg0)
  XLOAD(xb1, 1)
  STAGE_E(2, 2, cg0)

  int xkt = 2;                 // kt of next XLOAD (t+2)
  int nkt = 3, ncol0 = cg0;    // kt/col of next STAGE (t+3)
  int kc = 0, scol0 = cg0;     // current-tile kstep counter / SELECT strip base

  // main: 95 groups x 4 bodies = t 0..379
#pragma unroll 1
  for (int g = 0; g < 95; ++g) {
    BODY(0, xb0, 1, 1, "s_waitcnt vmcnt(12)")
    BODY(1, xb1, 1, 1, "s_waitcnt vmcnt(12)")
    BODY(2, xb0, 1, 1, "s_waitcnt vmcnt(12)")
    BODY(3, xb1, 1, 1, "s_waitcnt vmcnt(12)")
  }
  // tail: t=380..383
  BODY(0, xb0, 1, 1, "s_waitcnt vmcnt(12)")
  BODY(1, xb1, 1, 0, "s_waitcnt vmcnt(12)")
  BODY(2, xb0, 0, 0, "s_waitcnt vmcnt(8)")
  BODY(3, xb1, 0, 0, "s_waitcnt vmcnt(0)")
#undef BODY
#undef SELECT
#undef COMPUTE
#undef XLOAD
#undef STAGE_E

  // h-merge (lanes l and l+32 hold same x-row)
#pragma unroll
  for (int xj = 0; xj < 2; ++xj) {
    float ov[8]; int oi[8];
#pragma unroll
    for (int c = 0; c < 8; ++c) {
      ov[c] = __shfl_xor(bv[xj][c], 32, 64);
      oi[c] = __shfl_xor(bi[xj][c], 32, 64);
    }
#pragma unroll
    for (int c = 0; c < 8; ++c) ins8(bv[xj], bi[xj], ov[c], oi[c]);
  }

  // cross-wc merge via LDS (ring buffers dead now)
  __syncthreads();
  float* mval = (float*)&esm[0][0];
  int*   midx = (int*)&esm[1][0];
  if (wc == 1 && l < 32) {
#pragma unroll
    for (int xj = 0; xj < 2; ++xj) {
      const int rr = wr * 64 + xj * 32 + l31;
#pragma unroll
      for (int c = 0; c < 8; ++c) {
        mval[rr * 8 + c] = bv[xj][c];
        midx[rr * 8 + c] = bi[xj][c];
      }
    }
  }
  __syncthreads();
  if (wc == 0 && l < 32) {
#pragma unroll
    for (int xj = 0; xj < 2; ++xj) {
      const int rr = wr * 64 + xj * 32 + l31;
#pragma unroll
      for (int c = 0; c < 8; ++c) ins8(bv[xj], bi[xj], mval[rr * 8 + c], midx[rr * 8 + c]);
      unsigned short* dst = topp + (size_t)(row0 + rr) * 16 + chalf * 8;
#pragma unroll
      for (int c = 0; c < 8; ++c) dst[c] = (unsigned short)bi[xj][c];
    }
  }
}

// ---------------------------------------------------------------- stage 2: exact fp32 refine of 16 candidates
__global__ __launch_bounds__(256)
void vq_refine16(const float* __restrict__ x, const float* __restrict__ E,
                 const float* __restrict__ x2, const float* __restrict__ e2,
                 const unsigned short* __restrict__ topp, float* __restrict__ out) {
  const int gid = blockIdx.x * 256 + threadIdx.x;
  const int row = gid >> 4;
  const int s = gid & 15;
  const int myc = topp[(size_t)row * 16 + s];

  const float4* xr = (const float4*)(x + (size_t)row * DIM);
  const float4* er = (const float4*)(E + (size_t)myc * DIM);
  // two sequential fp32 fma chains split at KSPLIT (identical to R4's verified arithmetic)
  float accA = 0.f, accB = 0.f;
#pragma unroll 8
  for (int q = 0; q < KSPLIT / 4; ++q) {
    const float4 a = xr[q], b = er[q];
    accA = fmaf(a.x, b.x, accA); accA = fmaf(a.y, b.y, accA);
    accA = fmaf(a.z, b.z, accA); accA = fmaf(a.w, b.w, accA);
  }
#pragma unroll 8
  for (int q = KSPLIT / 4; q < DIM / 4; ++q) {
    const float4 a = xr[q], b = er[q];
    accB = fmaf(a.x, b.x, accB); accB = fmaf(a.y, b.y, accB);
    accB = fmaf(a.z, b.z, accB); accB = fmaf(a.w, b.w, accB);
  }
  const float d = fmaf(-2.0f, accA + accB, x2[row] + e2[myc]);

  // gather all 16 candidates of this row within the 16-lane group
  const int base = (threadIdx.x & 63) & ~15;
  float dv[16]; int cv[16];
#pragma unroll
  for (int t = 0; t < 16; ++t) {
    dv[t] = __shfl(d, base + t, 64);
    cv[t] = __shfl(myc, base + t, 64);
  }
  // 4 bubble passes -> slots 0..3 are the exact ascending top-4
#pragma unroll
  for (int a = 0; a < 4; ++a)
#pragma unroll
    for (int b = 15; b > a; --b) {
      const bool sw = (dv[b] < dv[b - 1]) || (dv[b] == dv[b - 1] && cv[b] < cv[b - 1]);
      if (sw) {
        float td = dv[b]; dv[b] = dv[b - 1]; dv[b - 1] = td;
        int ti = cv[b]; cv[b] = cv[b - 1]; cv[b - 1] = ti;
      }
    }

  if (s == 0) {
    out[EI_OFF + row] = (float)cv[0];
    const double d1 = (double)dv[1], d2 = (double)dv[2], d3 = (double)dv[3];
    double nrm = sqrt(d1 * d1 + d2 * d2 + d3 * d3);
    nrm = fmax(nrm, 1e-12);
    const double t1 = 1.0 / (d1 / nrm + 1e-4);
    const double t2 = 1.0 / (d2 / nrm + 1e-4);
    const double t3 = 1.0 / (d3 / nrm + 1e-4);
    const double mx = fmax(t1, fmax(t2, t3));
    const double e1 = exp(t1 - mx), e2x = exp(t2 - mx), e3 = exp(t3 - mx);
    const double sm = e1 + e2x + e3;
    out[TV_OFF + row * 3 + 0] = (float)(e1 / sm);
    out[TV_OFF + row * 3 + 1] = (float)(e2x / sm);
    out[TV_OFF + row * 3 + 2] = (float)(e3 / sm);
    out[TI_OFF + row * 3 + 0] = (float)cv[1];
    out[TI_OFF + row * 3 + 1] = (float)cv[2];
    out[TI_OFF + row * 3 + 2] = (float)cv[3];
  }

  // quantize = embed[argmin]: 16-lane cooperative float4 copy
  const float4* src = (const float4*)(E + (size_t)cv[0] * DIM);
  float4* dst = (float4*)(out + Q_OFF + (size_t)row * DIM);
#pragma unroll
  for (int k = 0; k < 12; ++k) dst[s + k * 16] = src[s + k * 16];
}

// ---------------------------------------------------------------- fallback: R4's passing fused fp32 kernel
__global__ __launch_bounds__(NT, 4)
void vq_main(const float* __restrict__ A, const float* __restrict__ E,
             const float* __restrict__ x2, const float* __restrict__ e2,
             float* __restrict__ out) {
  __shared__ float a_s[BK][BM + 4];
  __shared__ float b_s[BK][BN + 4];

  const int tid = threadIdx.x;
  const int tx = tid & 15;
  const int ty = tid >> 4;
  const int row0 = blockIdx.x * BM;

  const float x2r[2] = { x2[row0 + ty * 2 + 0], x2[row0 + ty * 2 + 1] };

  float bv[2][4];
  int   bi[2][4];
#pragma unroll
  for (int i = 0; i < 2; i++)
#pragma unroll
    for (int c = 0; c < 4; c++) { bv[i][c] = FLT_MAX; bi[i][c] = 0x7FFFFFFF; }

#define GEMM_STEP(k0, ACC)                                                       \
    {                                                                            \
      __syncthreads();                                                           \
      {                                                                          \
        const int r = tid >> 3, kq = tid & 7;                                    \
        const float4 v = *(const float4*)(A + (size_t)(row0 + r) * DIM + (k0 + kq * 4)); \
        a_s[kq * 4 + 0][r] = v.x; a_s[kq * 4 + 1][r] = v.y;                      \
        a_s[kq * 4 + 2][r] = v.z; a_s[kq * 4 + 3][r] = v.w;                      \
        _Pragma("unroll")                                                        \
        for (int s = 0; s < 2; s++) {                                            \
          const int fi = tid + s * NT;                                           \
          const int rb = fi >> 3, kb = fi & 7;                                   \
          const float4 w = *(const float4*)(E + (size_t)(col0 + rb) * DIM + (k0 + kb * 4)); \
          b_s[kb * 4 + 0][rb] = w.x; b_s[kb * 4 + 1][rb] = w.y;                  \
          b_s[kb * 4 + 2][rb] = w.z; b_s[kb * 4 + 3][rb] = w.w;                  \
        }                                                                        \
      }                                                                          \
      __syncthreads();                                                           \
      _Pragma("unroll")                                                          \
      for (int k = 0; k < BK; k++) {                                             \
        const float2 a2 = *(const float2*)&a_s[k][ty * 2];                       \
        float br[8];                                                             \
        *(float4*)(br)     = *(const float4*)&b_s[k][tx * 8];                    \
        *(float4*)(br + 4) = *(const float4*)&b_s[k][tx * 8 + 4];                \
        _Pragma("unroll")                                                        \
        for (int j = 0; j < 8; j++) {                                            \
          ACC[0][j] = fmaf(a2.x, br[j], ACC[0][j]);                              \
          ACC[1][j] = fmaf(a2.y, br[j], ACC[1][j]);                              \
        }                                                                        \
      }                                                                          \
    }

  for (int ct = 0; ct < NTOK / BN; ++ct) {
    const int col0 = ct * BN;

    float accA[2][8], accB[2][8];
#pragma unroll
    for (int i = 0; i < 2; i++)
#pragma unroll
      for (int j = 0; j < 8; j++) { accA[i][j] = 0.f; accB[i][j] = 0.f; }

    for (int k0 = 0; k0 < KSPLIT; k0 += BK) GEMM_STEP(k0, accA)
    for (int k0 = KSPLIT; k0 < DIM; k0 += BK) GEMM_STEP(k0, accB)

    float e2v[8];
    *(float4*)(e2v)     = *(const float4*)(e2 + col0 + tx * 8);
    *(float4*)(e2v + 4) = *(const float4*)(e2 + col0 + tx * 8 + 4);
#pragma unroll
    for (int i = 0; i < 2; i++) {
#pragma unroll
      for (int j = 0; j < 8; j++) {
        const float dot = accA[i][j] + accB[i][j];
        const float se = x2r[i] + e2v[j];
        const float d = fmaf(-2.0f, dot, se);
        const int ci = col0 + tx * 8 + j;
        ins4(bv[i], bi[i], d, ci);
      }
    }
  }
#undef GEMM_STEP

#pragma unroll
  for (int m = 1; m < 16; m <<= 1) {
#pragma unroll
    for (int i = 0; i < 2; i++) {
      float ov[4]; int oi[4];
#pragma unroll
      for (int c = 0; c < 4; c++) {
        ov[c] = __shfl_xor(bv[i][c], m, 64);
        oi[c] = __shfl_xor(bi[i][c], m, 64);
      }
#pragma unroll
      for (int c = 0; c < 4; c++) ins4(bv[i], bi[i], ov[c], oi[c]);
    }
  }

#pragma unroll
  for (int i = 0; i < 2; i++) {
    if (tx == i) {
      const int gr = row0 + ty * 2 + i;
      out[EI_OFF + gr] = (float)bi[i][0];
      const double d1 = (double)bv[i][1], d2 = (double)bv[i][2], d3 = (double)bv[i][3];
      double nrm = sqrt(d1 * d1 + d2 * d2 + d3 * d3);
      nrm = fmax(nrm, 1e-12);
      const double t1 = 1.0 / (d1 / nrm + 1e-4);
      const double t2 = 1.0 / (d2 / nrm + 1e-4);
      const double t3 = 1.0 / (d3 / nrm + 1e-4);
      const double mx = fmax(t1, fmax(t2, t3));
      const double e1 = exp(t1 - mx), e2x = exp(t2 - mx), e3 = exp(t3 - mx);
      const double s = e1 + e2x + e3;
      out[TV_OFF + gr * 3 + 0] = (float)(e1 / s);
      out[TV_OFF + gr * 3 + 1] = (float)(e2x / s);
      out[TV_OFF + gr * 3 + 2] = (float)(e3 / s);
      out[TI_OFF + gr * 3 + 0] = (float)bi[i][1];
      out[TI_OFF + gr * 3 + 1] = (float)bi[i][2];
      out[TI_OFF + gr * 3 + 2] = (float)bi[i][3];
    }
  }

  __syncthreads();
  int* idx_sh = (int*)&a_s[0][0];
  if (tx == 0) idx_sh[ty * 2 + 0] = bi[0][0];
  if (tx == 1) idx_sh[ty * 2 + 1] = bi[1][0];
  __syncthreads();

  for (int f = tid; f < BM * (DIM / 4); f += NT) {
    const int r = f / (DIM / 4);
    const int c = f % (DIM / 4);
    const int e = idx_sh[r];
    const float4 v = *(const float4*)(E + (size_t)e * DIM + c * 4);
    *(float4*)(out + Q_OFF + (size_t)(row0 + r) * DIM + c * 4) = v;
  }
}

// ---------------------------------------------------------------- launch
extern "C" void kernel_launch(void* const* d_in, const int* in_sizes, int n_in,
                              void* d_out, int out_size, void* d_ws, size_t ws_size,
                              hipStream_t stream) {
  const float* x = (const float*)d_in[0];  // inputs_flatten [32768,768]
  const float* E = (const float*)d_in[1];  // embed          [8192,768]
  float* out = (float*)d_out;

  // ws layout (bytes) — identical footprint to R5-R13 (proven to fit)
  unsigned char* ws = (unsigned char*)d_ws;
  float* e2 = (float*)ws;                                   // 8192 f32
  float* x2 = (float*)(ws + 32768);                         // 32768 f32
  unsigned short* topp = (unsigned short*)(ws + 32768 + 131072);  // 32768*16 u16 = 1MB
  unsigned short* xbT = (unsigned short*)(ws + 32768 + 131072 + 1048576);
  unsigned short* ebT = xbT + (size_t)NROWS * DIM;
  const size_t need = 32768 + 131072 + 1048576 +
                      (size_t)NROWS * DIM * 2 + (size_t)NTOK * DIM * 2;

  np_norm_kernel<<<NTOK / 4, 256, 0, stream>>>(E, e2);
  np_norm_kernel<<<NROWS / 4, 256, 0, stream>>>(x, x2);

  if (ws_size >= need) {
    cvtT_kernel<<<dim3(NROWS / 256, DIM / 8), 256, 0, stream>>>(x, xbT, NROWS);
    cvtT_kernel<<<dim3(NTOK / 256, DIM / 8), 256, 0, stream>>>(E, ebT, NTOK);
    vq_rank<<<512, 256, 0, stream>>>(xbT, ebT, e2, topp);
    vq_refine16<<<NROWS * 16 / 256, 256, 0, stream>>>(x, E, x2, e2, topp, out);
  } else {
    vq_main<<<NROWS / BM, NT, 0, stream>>>(x, E, x2, e2, out);
  }
}

// Round 15
// 884.913 us; speedup vs baseline: 1.6148x; 1.0460x over previous
//
#include <hip/hip_runtime.h>
#include <cfloat>
#include <cmath>

#define NROWS 32768
#define NTOK  8192
#define DIM   768
#define KSPLIT 384   // OpenBLAS sgemm kc — K=768 -> two sequential fp32 chains (verified R4)

// fallback (R4) tiling
#define BM 64
#define BN 128
#define BK 32
#define NT 512

// float offsets in d_out (concatenated outputs, all read back as f32)
#define Q_OFF   0
#define EI_OFF  (NROWS*DIM)          // 25165824
#define TV_OFF  (EI_OFF + NROWS)     // 25198592
#define TI_OFF  (TV_OFF + NROWS*3)   // 25296896

// screening margin: sound if >= 2*eps where eps = worst-case |bf16 dot - fp32 dot| (~3.8 here)
#define SCREEN_M 10.0f

typedef short short8 __attribute__((ext_vector_type(8)));
typedef float f32x4 __attribute__((ext_vector_type(4)));
typedef float f32x16 __attribute__((ext_vector_type(16)));

// ---------------------------------------------------------------- numpy-exact row sum of squares
// (verified bit-exact in R4 — do not touch)
__global__ __launch_bounds__(256)
void np_norm_kernel(const float* __restrict__ x, float* __restrict__ o) {
#pragma clang fp contract(off)
  const int wid = (blockIdx.x * 256 + threadIdx.x) >> 6;  // one wave per row
  const int lane = threadIdx.x & 63;
  const float* p = x + (size_t)wid * DIM + (lane >> 3) * 96 + (lane & 7);
  float v = p[0];
  float r = v * v;
#pragma unroll
  for (int k = 1; k < 12; k++) {
    float w = p[8 * k];
    float sq = w * w;
    r = r + sq;
  }
#pragma unroll
  for (int m = 1; m < 64; m <<= 1) {
    float other = __shfl_xor(r, m, 64);
    r = r + other;
  }
  if (lane == 0) o[wid] = r;
}

// ---------------------------------------------------------------- helpers
__device__ __forceinline__ bool dless(float a, int ai, float b, int bi_) {
  return (a < b) || (a == b && ai < bi_);
}

__device__ __forceinline__ void ins4(float (&v)[4], int (&x)[4], float c, int ci) {
  if (dless(c, ci, v[3], x[3])) {
    v[3] = c; x[3] = ci;
    if (dless(v[3], x[3], v[2], x[2])) { float tv = v[2]; int ti = x[2]; v[2] = v[3]; x[2] = x[3]; v[3] = tv; x[3] = ti; }
    if (dless(v[2], x[2], v[1], x[1])) { float tv = v[1]; int ti = x[1]; v[1] = v[2]; x[1] = x[2]; v[2] = tv; x[2] = ti; }
    if (dless(v[1], x[1], v[0], x[0])) { float tv = v[0]; int ti = x[0]; v[0] = v[1]; x[0] = x[1]; v[1] = tv; x[1] = ti; }
  }
}

// merge-path insert (with index tie-break, identical semantics to R9 merges)
__device__ __forceinline__ void ins8(float (&v)[8], int (&x)[8], float c, int ci) {
  if (dless(c, ci, v[7], x[7])) {
    v[7] = c; x[7] = ci;
#pragma unroll
    for (int k = 7; k > 0; k--) {
      if (dless(v[k], x[k], v[k - 1], x[k - 1])) {
        float tv = v[k - 1]; int ti = x[k - 1];
        v[k - 1] = v[k]; x[k - 1] = x[k];
        v[k] = tv; x[k] = ti;
      }
    }
  }
}

// hot-path insert: caller guarantees c < v[7]; branchless min/max levels, value-only order
__device__ __forceinline__ void ins8v(float (&v)[8], int (&x)[8], float c, int ci) {
  v[7] = c; x[7] = ci;
#pragma unroll
  for (int k = 7; k > 0; k--) {
    const bool sw = v[k] < v[k - 1];
    const float vmin = fminf(v[k], v[k - 1]);
    const float vmax = fmaxf(v[k], v[k - 1]);
    const int xk1 = sw ? x[k] : x[k - 1];
    const int xk  = sw ? x[k - 1] : x[k];
    v[k - 1] = vmin; v[k] = vmax;
    x[k - 1] = xk1;  x[k] = xk;
  }
}

__device__ __forceinline__ unsigned short f2bf(float f) {  // RNE fp32 -> bf16
  unsigned int u = __float_as_uint(f);
  u += 0x7FFFu + ((u >> 16) & 1u);
  return (unsigned short)(u >> 16);
}

typedef const __attribute__((address_space(1))) void* gas1_t;
typedef __attribute__((address_space(3))) void* las3_t;
__device__ __forceinline__ void gl16(const void* g, void* s) {
  // async global->LDS, 16B per lane; LDS dest = wave-uniform base + lane*16
  __builtin_amdgcn_global_load_lds((gas1_t)g, (las3_t)s, 16, 0, 0);
}

// ---------------------------------------------------------------- bf16 transposed pre-convert
// out layout: 16B chunk (Q, row) at out + (Q*nrows + row)*8 ushorts, Q = k-octet (0..95)
__global__ __launch_bounds__(256)
void cvtT_kernel(const float* __restrict__ in, unsigned short* __restrict__ out, int nrows) {
  const int row = blockIdx.x * 256 + threadIdx.x;
  const int Q = blockIdx.y;
  const float4* p = (const float4*)(in + (size_t)row * DIM + Q * 8);
  const float4 a = p[0], b = p[1];
  union { unsigned short u[8]; int4 v; } pk;
  pk.u[0] = f2bf(a.x); pk.u[1] = f2bf(a.y); pk.u[2] = f2bf(a.z); pk.u[3] = f2bf(a.w);
  pk.u[4] = f2bf(b.x); pk.u[5] = f2bf(b.y); pk.u[6] = f2bf(b.z); pk.u[7] = f2bf(b.w);
  *(int4*)(out + ((size_t)Q * nrows + row) * 8) = pk.v;
}

// ---------------------------------------------------------------- stage 1: swapped-operand MFMA rank
// 256-thread blocks (4 waves, 2wr x 2wc), tile 128 rows x 4096 cols, 2 blocks/CU.
// e-only LDS ring-4 (64KB) + counted vmcnt(12); x direct from global (L3-resident)
// with 2-deep register ping-pong prefetch. Per-candidate screened branchless ins8v.
// Epilogue: slots 4..7 beyond (half-4th + SCREEN_M) are written 0xFFFF (provably
// can't be exact union top-4) -> refine skips their gather+dot.
#define STRIPS 16
#define KSTEPS 24
#define NITER (STRIPS * KSTEPS)

__global__ __launch_bounds__(256, 2)
void vq_rank(const unsigned short* __restrict__ xbT, const unsigned short* __restrict__ ebT,
             const float* __restrict__ e2g, unsigned short* __restrict__ topp) {
  __shared__ __align__(16) unsigned char esm[4][16384];  // [buf][kq 0..3][col 0..255] 16B chunks

  const int tid = threadIdx.x;
  const int l = tid & 63;
  const int w = tid >> 6;          // 0..3
  const int wr = w >> 1, wc = w & 1;
  const int l31 = l & 31, h = l >> 5;

  // bijective XCD swizzle (512 blocks % 8 == 0); same-XCD blocks share the e col-half
  const int bid = (int)blockIdx.x;
  const int sbid = (bid & 7) * 64 + (bid >> 3);
  const int chalf = sbid >> 8;
  const int row0 = (sbid & 255) * 128;
  const int cg0 = chalf * 4096;

  // per-lane x bases (ushort units): Q = 4*kt + 2*s + h, row = row0 + wr*64 + xj*32 + l31
  const size_t xinv0 = ((size_t)h * NROWS + row0 + wr * 64 + l31) * 8;
  const size_t xinv1 = xinv0 + 32 * 8;

  float bv[2][8]; int bi[2][8];
#pragma unroll
  for (int xj = 0; xj < 2; ++xj)
#pragma unroll
    for (int c = 0; c < 8; ++c) { bv[xj][c] = FLT_MAX; bi[xj][c] = 0x7FFFFFFF; }

  f32x16 acc[4][2];
#pragma unroll
  for (int ei = 0; ei < 4; ++ei)
#pragma unroll
    for (int xj = 0; xj < 2; ++xj) acc[ei][xj] = (f32x16)0.f;

  short8 xb0[4], xb1[4];   // ping-pong x-fragment banks [s*2+xj]

#define STAGE_E(BN_, KT, COL0)                                                  \
  {                                                                             \
    const unsigned short* eg = ebT + ((size_t)(4 * (KT)) * NTOK + (COL0) + tid) * 8; \
    gl16(eg,                &esm[BN_][(0 * 256 + w * 64) * 16]);                \
    gl16(eg + NTOK * 8,     &esm[BN_][(1 * 256 + w * 64) * 16]);                \
    gl16(eg + 2 * NTOK * 8, &esm[BN_][(2 * 256 + w * 64) * 16]);                \
    gl16(eg + 3 * NTOK * 8, &esm[BN_][(3 * 256 + w * 64) * 16]);                \
  }

#define XLOAD(XB, KT)                                                           \
  {                                                                             \
    const unsigned short* xp = xbT + (size_t)(4 * (KT)) * (NROWS * 8);          \
    XB[0] = *(const short8*)(xp + xinv0);                                       \
    XB[1] = *(const short8*)(xp + xinv1);                                       \
    XB[2] = *(const short8*)(xp + 2 * NROWS * 8 + xinv0);                       \
    XB[3] = *(const short8*)(xp + 2 * NROWS * 8 + xinv1);                       \
  }

#define COMPUTE(B_, XB)                                                         \
  {                                                                             \
    const unsigned char* ebp = &esm[B_][0];                                     \
    __builtin_amdgcn_s_setprio(1);                                              \
    _Pragma("unroll")                                                           \
    for (int s = 0; s < 2; ++s) {                                               \
      const int kq = s * 2 + h;                                                 \
      short8 af[4];                                                             \
      _Pragma("unroll")                                                         \
      for (int ei = 0; ei < 4; ++ei)                                            \
        af[ei] = *(const short8*)(ebp + (size_t)(kq * 256 + wc * 128 + ei * 32 + l31) * 16); \
      _Pragma("unroll")                                                         \
      for (int ei = 0; ei < 4; ++ei)                                            \
        _Pragma("unroll")                                                       \
        for (int xj = 0; xj < 2; ++xj)                                          \
          acc[ei][xj] = __builtin_amdgcn_mfma_f32_32x32x16_bf16(af[ei], XB[s * 2 + xj], acc[ei][xj], 0, 0, 0); \
    }                                                                           \
    __builtin_amdgcn_s_setprio(0);                                              \
  }

  // SELECT: s = e2[col] - 2*dot (x2 row-constant: rank-invariant); per-candidate screen
#define SELECT(SC0)                                                             \
  {                                                                             \
    _Pragma("unroll")                                                           \
    for (int ei = 0; ei < 4; ++ei) {                                            \
      const int cb = (SC0) + wc * 128 + ei * 32 + 4 * h;                        \
      float4 e2q[4];                                                            \
      _Pragma("unroll")                                                         \
      for (int q = 0; q < 4; ++q)                                               \
        e2q[q] = *(const float4*)(e2g + cb + q * 8);                            \
      _Pragma("unroll")                                                         \
      for (int xj = 0; xj < 2; ++xj) {                                          \
        _Pragma("unroll")                                                       \
        for (int q = 0; q < 4; ++q) {                                           \
          const float c0 = fmaf(-2.f, acc[ei][xj][q * 4 + 0], e2q[q].x);        \
          const float c1 = fmaf(-2.f, acc[ei][xj][q * 4 + 1], e2q[q].y);        \
          const float c2 = fmaf(-2.f, acc[ei][xj][q * 4 + 2], e2q[q].z);        \
          const float c3 = fmaf(-2.f, acc[ei][xj][q * 4 + 3], e2q[q].w);        \
          if (c0 < bv[xj][7]) ins8v(bv[xj], bi[xj], c0, cb + q * 8 + 0);        \
          if (c1 < bv[xj][7]) ins8v(bv[xj], bi[xj], c1, cb + q * 8 + 1);        \
          if (c2 < bv[xj][7]) ins8v(bv[xj], bi[xj], c2, cb + q * 8 + 2);        \
          if (c3 < bv[xj][7]) ins8v(bv[xj], bi[xj], c3, cb + q * 8 + 3);        \
        }                                                                       \
      }                                                                         \
    }                                                                           \
    _Pragma("unroll")                                                           \
    for (int ei = 0; ei < 4; ++ei)                                              \
      _Pragma("unroll")                                                         \
      for (int xj = 0; xj < 2; ++xj) acc[ei][xj] = (f32x16)0.f;                 \
  }

#define BODY(B_, XB, DO_X, DO_S, WAITS)                                         \
  {                                                                             \
    asm volatile(WAITS ::: "memory");                                           \
    __builtin_amdgcn_s_barrier();                                               \
    asm volatile("" ::: "memory");                                              \
    COMPUTE(B_, XB)                                                             \
    if (DO_X) { XLOAD(XB, xkt) if (++xkt == KSTEPS) xkt = 0; }                  \
    if (DO_S) {                                                                 \
      STAGE_E((B_ + 3) & 3, nkt, ncol0)                                         \
      if (++nkt == KSTEPS) { nkt = 0; ncol0 += 256; }                           \
    }                                                                           \
    if (++kc == KSTEPS) { SELECT(scol0) kc = 0; scol0 += 256; }                 \
  }

  // prologue: e tiles 0..2 interleaved with x banks for t=0,1 (FIFO: S0,X0,S1,X1,S2)
  STAGE_E(0, 0, cg0)
  XLOAD(xb0, 0)
  STAGE_E(1, 1, cg0)
  XLOAD(xb1, 1)
  STAGE_E(2, 2, cg0)

  int xkt = 2;                 // kt of next XLOAD (t+2)
  int nkt = 3, ncol0 = cg0;    // kt/col of next STAGE (t+3)
  int kc = 0, scol0 = cg0;     // current-tile kstep counter / SELECT strip base

  // main: 95 groups x 4 bodies = t 0..379
#pragma unroll 1
  for (int g = 0; g < 95; ++g) {
    BODY(0, xb0, 1, 1, "s_waitcnt vmcnt(12)")
    BODY(1, xb1, 1, 1, "s_waitcnt vmcnt(12)")
    BODY(2, xb0, 1, 1, "s_waitcnt vmcnt(12)")
    BODY(3, xb1, 1, 1, "s_waitcnt vmcnt(12)")
  }
  // tail: t=380..383
  BODY(0, xb0, 1, 1, "s_waitcnt vmcnt(12)")
  BODY(1, xb1, 1, 0, "s_waitcnt vmcnt(12)")
  BODY(2, xb0, 0, 0, "s_waitcnt vmcnt(8)")
  BODY(3, xb1, 0, 0, "s_waitcnt vmcnt(0)")
#undef BODY
#undef SELECT
#undef COMPUTE
#undef XLOAD
#undef STAGE_E

  // h-merge (lanes l and l+32 hold same x-row)
#pragma unroll
  for (int xj = 0; xj < 2; ++xj) {
    float ov[8]; int oi[8];
#pragma unroll
    for (int c = 0; c < 8; ++c) {
      ov[c] = __shfl_xor(bv[xj][c], 32, 64);
      oi[c] = __shfl_xor(bi[xj][c], 32, 64);
    }
#pragma unroll
    for (int c = 0; c < 8; ++c) ins8(bv[xj], bi[xj], ov[c], oi[c]);
  }

  // cross-wc merge via LDS (ring buffers dead now)
  __syncthreads();
  float* mval = (float*)&esm[0][0];
  int*   midx = (int*)&esm[1][0];
  if (wc == 1 && l < 32) {
#pragma unroll
    for (int xj = 0; xj < 2; ++xj) {
      const int rr = wr * 64 + xj * 32 + l31;
#pragma unroll
      for (int c = 0; c < 8; ++c) {
        mval[rr * 8 + c] = bv[xj][c];
        midx[rr * 8 + c] = bi[xj][c];
      }
    }
  }
  __syncthreads();
  if (wc == 0 && l < 32) {
#pragma unroll
    for (int xj = 0; xj < 2; ++xj) {
      const int rr = wr * 64 + xj * 32 + l31;
#pragma unroll
      for (int c = 0; c < 8; ++c) ins8(bv[xj], bi[xj], mval[rr * 8 + c], midx[rr * 8 + c]);
      unsigned short* dst = topp + (size_t)(row0 + rr) * 16 + chalf * 8;
      // slots 0..3: always kept (any union-top-4 element is top-4 within its half)
#pragma unroll
      for (int c = 0; c < 4; ++c) dst[c] = (unsigned short)bi[xj][c];
      // slots 4..7: screened — beyond half-4th + M provably can't be exact top-4
      const float thr = bv[xj][3] + SCREEN_M;
#pragma unroll
      for (int c = 4; c < 8; ++c)
        dst[c] = (bv[xj][c] > thr) ? (unsigned short)0xFFFFu : (unsigned short)bi[xj][c];
    }
  }
}

// ---------------------------------------------------------------- stage 2: exact fp32 refine of <=16 candidates
__global__ __launch_bounds__(256)
void vq_refine16(const float* __restrict__ x, const float* __restrict__ E,
                 const float* __restrict__ x2, const float* __restrict__ e2,
                 const unsigned short* __restrict__ topp, float* __restrict__ out) {
  const int gid = blockIdx.x * 256 + threadIdx.x;
  const int row = gid >> 4;
  const int s = gid & 15;
  const unsigned myc = topp[(size_t)row * 16 + s];

  float d = FLT_MAX;
  if (myc != 0xFFFFu) {
    const float4* xr = (const float4*)(x + (size_t)row * DIM);
    const float4* er = (const float4*)(E + (size_t)myc * DIM);
    // two sequential fp32 fma chains split at KSPLIT (identical to R4's verified arithmetic)
    float accA = 0.f, accB = 0.f;
#pragma unroll 8
    for (int q = 0; q < KSPLIT / 4; ++q) {
      const float4 a = xr[q], b = er[q];
      accA = fmaf(a.x, b.x, accA); accA = fmaf(a.y, b.y, accA);
      accA = fmaf(a.z, b.z, accA); accA = fmaf(a.w, b.w, accA);
    }
#pragma unroll 8
    for (int q = KSPLIT / 4; q < DIM / 4; ++q) {
      const float4 a = xr[q], b = er[q];
      accB = fmaf(a.x, b.x, accB); accB = fmaf(a.y, b.y, accB);
      accB = fmaf(a.z, b.z, accB); accB = fmaf(a.w, b.w, accB);
    }
    d = fmaf(-2.0f, accA + accB, x2[row] + e2[myc]);
  }

  // gather all 16 candidates of this row within the 16-lane group
  const int base = (threadIdx.x & 63) & ~15;
  float dv[16]; int cv[16];
#pragma unroll
  for (int t = 0; t < 16; ++t) {
    dv[t] = __shfl(d, base + t, 64);
    cv[t] = __shfl((int)myc, base + t, 64);
  }
  // 4 bubble passes -> slots 0..3 are the exact ascending top-4
  // (screened lanes carry FLT_MAX and >=8 real candidates always exist)
#pragma unroll
  for (int a = 0; a < 4; ++a)
#pragma unroll
    for (int b = 15; b > a; --b) {
      const bool sw = (dv[b] < dv[b - 1]) || (dv[b] == dv[b - 1] && cv[b] < cv[b - 1]);
      if (sw) {
        float td = dv[b]; dv[b] = dv[b - 1]; dv[b - 1] = td;
        int ti = cv[b]; cv[b] = cv[b - 1]; cv[b - 1] = ti;
      }
    }

  if (s == 0) {
    out[EI_OFF + row] = (float)cv[0];
    const double d1 = (double)dv[1], d2 = (double)dv[2], d3 = (double)dv[3];
    double nrm = sqrt(d1 * d1 + d2 * d2 + d3 * d3);
    nrm = fmax(nrm, 1e-12);
    const double t1 = 1.0 / (d1 / nrm + 1e-4);
    const double t2 = 1.0 / (d2 / nrm + 1e-4);
    const double t3 = 1.0 / (d3 / nrm + 1e-4);
    const double mx = fmax(t1, fmax(t2, t3));
    const double e1 = exp(t1 - mx), e2x = exp(t2 - mx), e3 = exp(t3 - mx);
    const double sm = e1 + e2x + e3;
    out[TV_OFF + row * 3 + 0] = (float)(e1 / sm);
    out[TV_OFF + row * 3 + 1] = (float)(e2x / sm);
    out[TV_OFF + row * 3 + 2] = (float)(e3 / sm);
    out[TI_OFF + row * 3 + 0] = (float)cv[1];
    out[TI_OFF + row * 3 + 1] = (float)cv[2];
    out[TI_OFF + row * 3 + 2] = (float)cv[3];
  }

  // quantize = embed[argmin]: 16-lane cooperative float4 copy (cv[0] always real)
  const float4* src = (const float4*)(E + (size_t)cv[0] * DIM);
  float4* dst = (float4*)(out + Q_OFF + (size_t)row * DIM);
#pragma unroll
  for (int k = 0; k < 12; ++k) dst[s + k * 16] = src[s + k * 16];
}

// ---------------------------------------------------------------- fallback: R4's passing fused fp32 kernel
__global__ __launch_bounds__(NT, 4)
void vq_main(const float* __restrict__ A, const float* __restrict__ E,
             const float* __restrict__ x2, const float* __restrict__ e2,
             float* __restrict__ out) {
  __shared__ float a_s[BK][BM + 4];
  __shared__ float b_s[BK][BN + 4];

  const int tid = threadIdx.x;
  const int tx = tid & 15;
  const int ty = tid >> 4;
  const int row0 = blockIdx.x * BM;

  const float x2r[2] = { x2[row0 + ty * 2 + 0], x2[row0 + ty * 2 + 1] };

  float bv[2][4];
  int   bi[2][4];
#pragma unroll
  for (int i = 0; i < 2; i++)
#pragma unroll
    for (int c = 0; c < 4; c++) { bv[i][c] = FLT_MAX; bi[i][c] = 0x7FFFFFFF; }

#define GEMM_STEP(k0, ACC)                                                       \
    {                                                                            \
      __syncthreads();                                                           \
      {                                                                          \
        const int r = tid >> 3, kq = tid & 7;                                    \
        const float4 v = *(const float4*)(A + (size_t)(row0 + r) * DIM + (k0 + kq * 4)); \
        a_s[kq * 4 + 0][r] = v.x; a_s[kq * 4 + 1][r] = v.y;                      \
        a_s[kq * 4 + 2][r] = v.z; a_s[kq * 4 + 3][r] = v.w;                      \
        _Pragma("unroll")                                                        \
        for (int s = 0; s < 2; s++) {                                            \
          const int fi = tid + s * NT;                                           \
          const int rb = fi >> 3, kb = fi & 7;                                   \
          const float4 w = *(const float4*)(E + (size_t)(col0 + rb) * DIM + (k0 + kb * 4)); \
          b_s[kb * 4 + 0][rb] = w.x; b_s[kb * 4 + 1][rb] = w.y;                  \
          b_s[kb * 4 + 2][rb] = w.z; b_s[kb * 4 + 3][rb] = w.w;                  \
        }                                                                        \
      }                                                                          \
      __syncthreads();                                                           \
      _Pragma("unroll")                                                          \
      for (int k = 0; k < BK; k++) {                                             \
        const float2 a2 = *(const float2*)&a_s[k][ty * 2];                       \
        float br[8];                                                             \
        *(float4*)(br)     = *(const float4*)&b_s[k][tx * 8];                    \
        *(float4*)(br + 4) = *(const float4*)&b_s[k][tx * 8 + 4];                \
        _Pragma("unroll")                                                        \
        for (int j = 0; j < 8; j++) {                                            \
          ACC[0][j] = fmaf(a2.x, br[j], ACC[0][j]);                              \
          ACC[1][j] = fmaf(a2.y, br[j], ACC[1][j]);                              \
        }                                                                        \
      }                                                                          \
    }

  for (int ct = 0; ct < NTOK / BN; ++ct) {
    const int col0 = ct * BN;

    float accA[2][8], accB[2][8];
#pragma unroll
    for (int i = 0; i < 2; i++)
#pragma unroll
      for (int j = 0; j < 8; j++) { accA[i][j] = 0.f; accB[i][j] = 0.f; }

    for (int k0 = 0; k0 < KSPLIT; k0 += BK) GEMM_STEP(k0, accA)
    for (int k0 = KSPLIT; k0 < DIM; k0 += BK) GEMM_STEP(k0, accB)

    float e2v[8];
    *(float4*)(e2v)     = *(const float4*)(e2 + col0 + tx * 8);
    *(float4*)(e2v + 4) = *(const float4*)(e2 + col0 + tx * 8 + 4);
#pragma unroll
    for (int i = 0; i < 2; i++) {
#pragma unroll
      for (int j = 0; j < 8; j++) {
        const float dot = accA[i][j] + accB[i][j];
        const float se = x2r[i] + e2v[j];
        const float d = fmaf(-2.0f, dot, se);
        const int ci = col0 + tx * 8 + j;
        ins4(bv[i], bi[i], d, ci);
      }
    }
  }
#undef GEMM_STEP

#pragma unroll
  for (int m = 1; m < 16; m <<= 1) {
#pragma unroll
    for (int i = 0; i < 2; i++) {
      float ov[4]; int oi[4];
#pragma unroll
      for (int c = 0; c < 4; c++) {
        ov[c] = __shfl_xor(bv[i][c], m, 64);
        oi[c] = __shfl_xor(bi[i][c], m, 64);
      }
#pragma unroll
      for (int c = 0; c < 4; c++) ins4(bv[i], bi[i], ov[c], oi[c]);
    }
  }

#pragma unroll
  for (int i = 0; i < 2; i++) {
    if (tx == i) {
      const int gr = row0 + ty * 2 + i;
      out[EI_OFF + gr] = (float)bi[i][0];
      const double d1 = (double)bv[i][1], d2 = (double)bv[i][2], d3 = (double)bv[i][3];
      double nrm = sqrt(d1 * d1 + d2 * d2 + d3 * d3);
      nrm = fmax(nrm, 1e-12);
      const double t1 = 1.0 / (d1 / nrm + 1e-4);
      const double t2 = 1.0 / (d2 / nrm + 1e-4);
      const double t3 = 1.0 / (d3 / nrm + 1e-4);
      const double mx = fmax(t1, fmax(t2, t3));
      const double e1 = exp(t1 - mx), e2x = exp(t2 - mx), e3 = exp(t3 - mx);
      const double s = e1 + e2x + e3;
      out[TV_OFF + gr * 3 + 0] = (float)(e1 / s);
      out[TV_OFF + gr * 3 + 1] = (float)(e2x / s);
      out[TV_OFF + gr * 3 + 2] = (float)(e3 / s);
      out[TI_OFF + gr * 3 + 0] = (float)bi[i][1];
      out[TI_OFF + gr * 3 + 1] = (float)bi[i][2];
      out[TI_OFF + gr * 3 + 2] = (float)bi[i][3];
    }
  }

  __syncthreads();
  int* idx_sh = (int*)&a_s[0][0];
  if (tx == 0) idx_sh[ty * 2 + 0] = bi[0][0];
  if (tx == 1) idx_sh[ty * 2 + 1] = bi[1][0];
  __syncthreads();

  for (int f = tid; f < BM * (DIM / 4); f += NT) {
    const int r = f / (DIM / 4);
    const int c = f % (DIM / 4);
    const int e = idx_sh[r];
    const float4 v = *(const float4*)(E + (size_t)e * DIM + c * 4);
    *(float4*)(out + Q_OFF + (size_t)(row0 + r) * DIM + c * 4) = v;
  }
}

// ---------------------------------------------------------------- launch
extern "C" void kernel_launch(void* const* d_in, const int* in_sizes, int n_in,
                              void* d_out, int out_size, void* d_ws, size_t ws_size,
                              hipStream_t stream) {
  const float* x = (const float*)d_in[0];  // inputs_flatten [32768,768]
  const float* E = (const float*)d_in[1];  // embed          [8192,768]
  float* out = (float*)d_out;

  // ws layout (bytes) — identical footprint to R5-R14 (proven to fit)
  unsigned char* ws = (unsigned char*)d_ws;
  float* e2 = (float*)ws;                                   // 8192 f32
  float* x2 = (float*)(ws + 32768);                         // 32768 f32
  unsigned short* topp = (unsigned short*)(ws + 32768 + 131072);  // 32768*16 u16 = 1MB
  unsigned short* xbT = (unsigned short*)(ws + 32768 + 131072 + 1048576);
  unsigned short* ebT = xbT + (size_t)NROWS * DIM;
  const size_t need = 32768 + 131072 + 1048576 +
                      (size_t)NROWS * DIM * 2 + (size_t)NTOK * DIM * 2;

  np_norm_kernel<<<NTOK / 4, 256, 0, stream>>>(E, e2);
  np_norm_kernel<<<NROWS / 4, 256, 0, stream>>>(x, x2);

  if (ws_size >= need) {
    cvtT_kernel<<<dim3(NROWS / 256, DIM / 8), 256, 0, stream>>>(x, xbT, NROWS);
    cvtT_kernel<<<dim3(NTOK / 256, DIM / 8), 256, 0, stream>>>(E, ebT, NTOK);
    vq_rank<<<512, 256, 0, stream>>>(xbT, ebT, e2, topp);
    vq_refine16<<<NROWS * 16 / 256, 256, 0, stream>>>(x, E, x2, e2, topp, out);
  } else {
    vq_main<<<NROWS / BM, NT, 0, stream>>>(x, E, x2, e2, out);
  }
}